// Round 8
// baseline (7633.189 us; speedup 1.0000x reference)
//
#include <hip/hip_runtime.h>
#include <hip/hip_bf16.h>

// Ternary-quantized linear: out[M,N] = x[M,K] . W^T,  W[n,k] = q[n,k]*scale[n].
// R8: occupancy 2->4 blocks/CU. Ring-3 -> double-buffer (40KB LDS), counted
//     vmcnt(5) kept (T4), TWO raw s_barriers per kt (write-after-read safety,
//     m201 pattern; no vmcnt drain at barriers). launch_bounds(256,4).
//     T5 setprio around COMPUTE (4 independent blocks/CU = role diversity).
//     Pre-pass + fragment geometry unchanged from R7. Fallback = R5 fused.

#define M_DIM 8192
#define N_DIM 11008
#define K_DIM 4096
#define BM 128
#define BN 256
#define BK 64
#define KT 64
#define NB_N (N_DIM / BN)          // 43
#define NWG ((M_DIM / BM) * NB_N)  // 2752, %8 == 0

#define XBF_BYTES ((size_t)M_DIM * K_DIM * 2)        // 67108864
#define BT_BYTES  ((size_t)N_DIM * K_DIM / 4)        // 11272192
#define WS_NEED   (XBF_BYTES + BT_BYTES)

typedef __attribute__((ext_vector_type(8))) short bf16x8;
typedef __attribute__((ext_vector_type(4))) float f32x4;

__device__ inline unsigned int bf16b(float f) {
  union { __hip_bfloat16 h; unsigned short u; } cv;
  cv.h = __float2bfloat16(f);
  return (unsigned int)cv.u;
}

__device__ __forceinline__ void gload_lds16(const void* g, void* l) {
  __builtin_amdgcn_global_load_lds(
      (const __attribute__((address_space(1))) unsigned int*)g,
      (__attribute__((address_space(3))) unsigned int*)l, 16, 0, 0);
}

// ---------------- pre-pass: x fp32->bf16 ; PW one-byte-per-int32 -> tight bytes
#define XCVT_BLOCKS 16384   // 16384*256*8 = 33554432 floats
#define PACK_BLOCKS 5504    // 5504*256*8  = 11272192 int32s
__global__ __launch_bounds__(256)
void prep_kernel(const float* __restrict__ X, const int* __restrict__ PW,
                 unsigned short* __restrict__ Xbf, unsigned char* __restrict__ Bt) {
  const int b = blockIdx.x;
  if (b < XCVT_BLOCKS) {
    const size_t i8 = ((size_t)b * 256 + threadIdx.x) * 8;
    float4 a = *(const float4*)(X + i8);
    float4 c = *(const float4*)(X + i8 + 4);
    uint4 o;
    o.x = bf16b(a.x) | (bf16b(a.y) << 16);
    o.y = bf16b(a.z) | (bf16b(a.w) << 16);
    o.z = bf16b(c.x) | (bf16b(c.y) << 16);
    o.w = bf16b(c.z) | (bf16b(c.w) << 16);
    *(uint4*)(Xbf + i8) = o;
  } else {
    const size_t i8 = ((size_t)(b - XCVT_BLOCKS) * 256 + threadIdx.x) * 8;
    int4 p = *(const int4*)(PW + i8);
    int4 q = *(const int4*)(PW + i8 + 4);
    uint2 o;
    o.x = (unsigned)(p.x & 255) | ((unsigned)(p.y & 255) << 8) |
          ((unsigned)(p.z & 255) << 16) | ((unsigned)(p.w & 255) << 24);
    o.y = (unsigned)(q.x & 255) | ((unsigned)(q.y & 255) << 8) |
          ((unsigned)(q.z & 255) << 16) | ((unsigned)(q.w & 255) << 24);
    *(uint2*)(Bt + i8) = o;
  }
}

// ---------------- main MFMA GEMM (A bf16 from ws, B tight-packed from ws) ----
__global__ __launch_bounds__(256, 4)
void qlin_main_kernel(const unsigned short* __restrict__ Xbf,
                      const unsigned char* __restrict__ Bt,
                      const float* __restrict__ SC, float* __restrict__ OUT) {
  __shared__ unsigned short As[2][BM * BK];  // 2 x 16 KB dbuf, 128B rows
  __shared__ unsigned char  Bs[2][BN * 16];  // 2 x 4 KB dbuf, packed, linear

  const int tid = threadIdx.x;
  const int lane = tid & 63;
  const int w = tid >> 6;

  const int wg = blockIdx.x;
  const int swz = (wg & 7) * (NWG / 8) + (wg >> 3);
  const int bm = swz / NB_N;
  const int bn = swz - bm * NB_N;

  // ---- A stage: 4 gload_lds/thread; linear LDS dest = wave base + lane*16.
  // LDS offset o = i*1024 + lane*16 -> row = w*32+i*8+(lane>>3), slot = lane&7.
  // Source chunk c = slot ^ (row&7); row&7 == lane>>3 (m173 pre-swizzled src).
  const int l3 = lane >> 3;
  const int asrc_c = (lane & 7) ^ l3;
  const char* ab0 = (const char*)Xbf +
      (size_t)(bm * BM + w * 32 + l3) * (K_DIM * 2) + asrc_c * 16;
  // ---- B stage: 1 gload_lds/wave; row (= W output col) w*64+lane, 16B per kt.
  const char* bb = (const char*)Bt + (size_t)(bn * BN + w * 64 + lane) * (K_DIM / 4);

#define STAGE(IDX, KT_) do {                                           \
    unsigned short* ad_ = &As[IDX][w * 2048];                          \
    unsigned char* bd_ = &Bs[IDX][w * 1024];                           \
    gload_lds16(ab0 + (KT_)*128,           ad_);                       \
    gload_lds16(ab0 + (KT_)*128 + 65536,   ad_ + 512);                 \
    gload_lds16(ab0 + (KT_)*128 + 131072,  ad_ + 1024);                \
    gload_lds16(ab0 + (KT_)*128 + 196608,  ad_ + 1536);                \
    gload_lds16(bb  + (KT_)*16,            bd_);                       \
  } while (0)

  f32x4 acc[8][4];
#pragma unroll
  for (int i = 0; i < 8; ++i)
#pragma unroll
    for (int j = 0; j < 4; ++j) acc[i][j] = (f32x4){0.f, 0.f, 0.f, 0.f};

  // ---- fragment read geometry ----
  const int l4 = lane >> 4;                 // 0..3
  const int axor = lane & 7;                // row&7 for A-frag chunk XOR
  const int arow = (lane & 15) * 128;       // A row byte offset (within m-tile)
  const int hb = l4 >> 1;                   // B dword-pair select
  const unsigned hoff = (unsigned)(l4 & 1) * 16;  // B 16-bit half select
  const int rbase = (w * 64 + (lane & 15)) * 16 + hb * 4;

#define COMPUTE(B_) do {                                                        \
    const char* asb_ = (const char*)&As[B_][0];                                 \
    const unsigned char* bsb_ = &Bs[B_][0];                                     \
    _Pragma("unroll")                                                           \
    for (int kk = 0; kk < 2; ++kk) {                                            \
      bf16x8 af[8];                                                             \
      _Pragma("unroll")                                                         \
      for (int m = 0; m < 8; ++m)                                               \
        af[m] = *(const bf16x8*)(asb_ + m * 2048 + arow +                       \
                                 (((kk * 4 + l4) ^ axor) << 4));                \
      _Pragma("unroll")                                                         \
      for (int n = 0; n < 4; ++n) {                                             \
        const unsigned d = *(const unsigned*)(bsb_ + rbase + n * 256 + kk * 8); \
        const unsigned w16 = (d >> hoff) & 0xFFFFu;                             \
        const unsigned u = w16 | (w16 << 14);                                   \
        union { uint4 s; bf16x8 v; } bfr;                                       \
        bfr.s.x = ((u << 14) & 0xC000C000u) + 0x40004000u;                      \
        bfr.s.y = ((u << 10) & 0xC000C000u) + 0x40004000u;                      \
        bfr.s.z = ((u << 6)  & 0xC000C000u) + 0x40004000u;                      \
        bfr.s.w = ((u << 2)  & 0xC000C000u) + 0x40004000u;                      \
        _Pragma("unroll")                                                       \
        for (int m = 0; m < 8; ++m)                                             \
          acc[m][n] = __builtin_amdgcn_mfma_f32_16x16x32_bf16(af[m], bfr.v,     \
                                                              acc[m][n], 0, 0, 0); \
      }                                                                         \
    }                                                                           \
  } while (0)

  // ---- main loop: double buffer, counted vmcnt, 2 raw barriers per kt ----
  STAGE(0, 0);                                   // 5 loads in flight
  int cur = 0;
  for (int kt = 0; kt < KT - 1; ++kt) {
    STAGE(cur ^ 1, kt + 1);                      // 10 in flight
    asm volatile("s_waitcnt vmcnt(5)" ::: "memory");   // cur's 5 done; nxt's stay
    __builtin_amdgcn_s_barrier();                // all waves: cur ready
    __builtin_amdgcn_s_setprio(1);
    COMPUTE(cur);
    __builtin_amdgcn_s_setprio(0);
    asm volatile("s_waitcnt lgkmcnt(0)" ::: "memory"); // my reads of cur done
    __builtin_amdgcn_s_barrier();                // all waves done reading cur
    cur ^= 1;
  }
  asm volatile("s_waitcnt vmcnt(0)" ::: "memory");     // tail: last buffer
  __builtin_amdgcn_s_barrier();
  COMPUTE(cur);
#undef STAGE
#undef COMPUTE

  // ---- epilogue: acc * (-0.5*scale[col]); C/D: col=lane&15, row=(lane>>4)*4+r
  const int gc0 = bn * BN + w * 64 + (lane & 15);
  const int gr0 = bm * BM + (l4 << 2);
  float sc[4];
#pragma unroll
  for (int n = 0; n < 4; ++n) sc[n] = -0.5f * SC[gc0 + n * 16];
#pragma unroll
  for (int m = 0; m < 8; ++m)
#pragma unroll
    for (int n = 0; n < 4; ++n)
#pragma unroll
      for (int r = 0; r < 4; ++r)
        OUT[(size_t)(gr0 + m * 16 + r) * N_DIM + gc0 + n * 16] = acc[m][n][r] * sc[n];
}

// ---------------- fallback: R5 fused kernel (used if ws too small) ----------
#define BSTRIDE 20
__global__ __launch_bounds__(256, 2)
void qlin_fused_kernel(const float* __restrict__ X, const int* __restrict__ PW,
                       const float* __restrict__ SC, float* __restrict__ OUT) {
  __shared__ unsigned short Asf[BM * BK];
  __shared__ unsigned char Bp[BN * BSTRIDE];

  const int tid = threadIdx.x;
  const int wg = blockIdx.x;
  const int swz = (wg & 7) * (NWG / 8) + (wg >> 3);
  const int bm = swz / NB_N;
  const int bn = swz - bm * NB_N;

  const int lane = tid & 63;
  const int wave = tid >> 6;
  const int wr = wave >> 1;
  const int wc = wave & 1;

  const int arow = tid >> 3;
  const int ac8  = tid & 7;
  const float* xptr = X + (size_t)(bm * BM + arow) * K_DIM + ac8 * 8;
  const unsigned int aswz = ((unsigned)arow & 7u) << 4;

  const int bc  = tid & 3;
  const int br0 = tid >> 2;
  const int* pwptr = PW + (size_t)(bn * BN + br0) * (K_DIM / 4) + bc * 4;
  const int bwoff = (bc & 1) * 8 + (bc >> 1) * 2;

  f32x4 acc[4][8];
#pragma unroll
  for (int i = 0; i < 4; ++i)
#pragma unroll
    for (int j = 0; j < 8; ++j) acc[i][j] = (f32x4){0.f, 0.f, 0.f, 0.f};

  float4 av[4][2];
  int4 bv[4];
#pragma unroll
  for (int j = 0; j < 4; ++j) {
    av[j][0] = *(const float4*)(xptr + (size_t)(32 * j) * K_DIM);
    av[j][1] = *(const float4*)(xptr + (size_t)(32 * j) * K_DIM + 4);
  }
#pragma unroll
  for (int j = 0; j < 4; ++j)
    bv[j] = *(const int4*)(pwptr + (size_t)(64 * j) * (K_DIM / 4));

  for (int kt = 0; kt < KT; ++kt) {
    __syncthreads();
#pragma unroll
    for (int j = 0; j < 4; ++j) {
      uint4 wv;
      wv.x = bf16b(av[j][0].x) | (bf16b(av[j][0].y) << 16);
      wv.y = bf16b(av[j][0].z) | (bf16b(av[j][0].w) << 16);
      wv.z = bf16b(av[j][1].x) | (bf16b(av[j][1].y) << 16);
      wv.w = bf16b(av[j][1].z) | (bf16b(av[j][1].w) << 16);
      *(uint4*)((char*)Asf + (arow + 32 * j) * 128 + (((unsigned)ac8 * 16u) ^ aswz)) = wv;
    }
#pragma unroll
    for (int j = 0; j < 4; ++j) {
      const unsigned int ulo = ((unsigned)bv[j].x & 255u) | (((unsigned)bv[j].y & 255u) << 8);
      const unsigned int uhi = ((unsigned)bv[j].z & 255u) | (((unsigned)bv[j].w & 255u) << 8);
      unsigned char* dst = Bp + (br0 + 64 * j) * BSTRIDE + bwoff;
      *(unsigned short*)(dst)     = (unsigned short)ulo;
      *(unsigned short*)(dst + 4) = (unsigned short)uhi;
    }
    __syncthreads();

    if (kt + 1 < KT) {
#pragma unroll
      for (int j = 0; j < 4; ++j) {
        av[j][0] = *(const float4*)(xptr + (kt + 1) * BK + (size_t)(32 * j) * K_DIM);
        av[j][1] = *(const float4*)(xptr + (kt + 1) * BK + (size_t)(32 * j) * K_DIM + 4);
      }
#pragma unroll
      for (int j = 0; j < 4; ++j)
        bv[j] = *(const int4*)(pwptr + (kt + 1) * 16 + (size_t)(64 * j) * (K_DIM / 4));
    }

    const int bh = lane >> 4;
    const int bcol0 = wc * 128 + (lane & 15);
    unsigned int d[8];
#pragma unroll
    for (int n = 0; n < 8; ++n)
      d[n] = *(const unsigned int*)(Bp + (bcol0 + n * 16) * BSTRIDE + bh * 4);

    const unsigned int rswz = ((unsigned)lane & 7u) << 4;
#pragma unroll
    for (int kk = 0; kk < 2; ++kk) {
      bf16x8 af[4];
      const unsigned int coff = (((unsigned)(kk * 4 + (lane >> 4))) * 16u) ^ rswz;
#pragma unroll
      for (int m = 0; m < 4; ++m)
        af[m] = *(const bf16x8*)((const char*)Asf + (wr * 64 + m * 16 + (lane & 15)) * 128 + coff);
#pragma unroll
      for (int n = 0; n < 8; ++n) {
        const unsigned int w16 = kk ? (d[n] >> 16) : (d[n] & 0xFFFFu);
        const unsigned int u = w16 | (w16 << 14);
        union { uint4 s; bf16x8 v; } bfr;
        bfr.s.x = ((u << 14) & 0xC000C000u) + 0x40004000u;
        bfr.s.y = ((u << 10) & 0xC000C000u) + 0x40004000u;
        bfr.s.z = ((u << 6)  & 0xC000C000u) + 0x40004000u;
        bfr.s.w = ((u << 2)  & 0xC000C000u) + 0x40004000u;
#pragma unroll
        for (int m = 0; m < 4; ++m)
          acc[m][n] = __builtin_amdgcn_mfma_f32_16x16x32_bf16(af[m], bfr.v, acc[m][n], 0, 0, 0);
      }
    }
  }

  const int gc0 = bn * BN + wc * 128 + (lane & 15);
  const int gr0 = bm * BM + wr * 64 + ((lane >> 4) << 2);
  float sc[8];
#pragma unroll
  for (int n = 0; n < 8; ++n) sc[n] = -0.5f * SC[gc0 + n * 16];
#pragma unroll
  for (int m = 0; m < 4; ++m)
#pragma unroll
    for (int n = 0; n < 8; ++n)
#pragma unroll
      for (int r = 0; r < 4; ++r)
        OUT[(size_t)(gr0 + m * 16 + r) * N_DIM + gc0 + n * 16] = acc[m][n][r] * sc[n];
}

extern "C" void kernel_launch(void* const* d_in, const int* in_sizes, int n_in,
                              void* d_out, int out_size, void* d_ws, size_t ws_size,
                              hipStream_t stream) {
  const float* x  = (const float*)d_in[0];
  const int*   pw = (const int*)d_in[1];
  const float* sc = (const float*)d_in[2];
  float* out = (float*)d_out;
  (void)in_sizes; (void)n_in; (void)out_size;

  if (ws_size >= WS_NEED) {
    unsigned short* xbf = (unsigned short*)d_ws;
    unsigned char* bt = (unsigned char*)d_ws + XBF_BYTES;
    prep_kernel<<<dim3(XCVT_BLOCKS + PACK_BLOCKS), dim3(256), 0, stream>>>(x, pw, xbf, bt);
    qlin_main_kernel<<<dim3(NWG), dim3(256), 0, stream>>>(xbf, bt, sc, out);
  } else {
    qlin_fused_kernel<<<dim3(NWG), dim3(256), 0, stream>>>(x, pw, sc, out);
  }
}

// Round 9
// 742.365 us; speedup vs baseline: 10.2823x; 10.2823x over previous
//
#include <hip/hip_runtime.h>
#include <hip/hip_bf16.h>

// Ternary-quantized linear: out[M,N] = x[M,K] . W^T,  W[n,k] = q[n,k]*scale[n].
// R9: fix R8's register cliff. Block tile 128x128, 4 waves (2x2), wave tile
//     64x64 -> acc[4][4]=64 AGPR + ~45 VGPR ~= 110/wave < 128 => 4 waves/SIMD
//     REALLY fits (R8's 128x64 wave tile needed 128 AGPR alone -> spilled).
//     Keeps: pre-pass, global_load_lds w/ pre-swizzled A source, packed-B LDS
//     + SWAR unpack, dbuf + counted vmcnt(5) + 2 raw barriers + setprio.
//     B staged by waves 0-1; waves 2-3 load into dummy LDS (uniform vmcnt).

#define M_DIM 8192
#define N_DIM 11008
#define K_DIM 4096
#define BM 128
#define BN 128
#define BK 64
#define KT 64
#define NB_N (N_DIM / BN)          // 86
#define NWG ((M_DIM / BM) * NB_N)  // 5504, %8 == 0

#define XBF_BYTES ((size_t)M_DIM * K_DIM * 2)        // 67108864
#define BT_BYTES  ((size_t)N_DIM * K_DIM / 4)        // 11272192
#define WS_NEED   (XBF_BYTES + BT_BYTES)

typedef __attribute__((ext_vector_type(8))) short bf16x8;
typedef __attribute__((ext_vector_type(4))) float f32x4;

__device__ inline unsigned int bf16b(float f) {
  union { __hip_bfloat16 h; unsigned short u; } cv;
  cv.h = __float2bfloat16(f);
  return (unsigned int)cv.u;
}

__device__ __forceinline__ void gload_lds16(const void* g, void* l) {
  __builtin_amdgcn_global_load_lds(
      (const __attribute__((address_space(1))) unsigned int*)g,
      (__attribute__((address_space(3))) unsigned int*)l, 16, 0, 0);
}

// ---------------- pre-pass: x fp32->bf16 ; PW one-byte-per-int32 -> tight bytes
#define XCVT_BLOCKS 16384   // 16384*256*8 = 33554432 floats
#define PACK_BLOCKS 5504    // 5504*256*8  = 11272192 int32s
__global__ __launch_bounds__(256)
void prep_kernel(const float* __restrict__ X, const int* __restrict__ PW,
                 unsigned short* __restrict__ Xbf, unsigned char* __restrict__ Bt) {
  const int b = blockIdx.x;
  if (b < XCVT_BLOCKS) {
    const size_t i8 = ((size_t)b * 256 + threadIdx.x) * 8;
    float4 a = *(const float4*)(X + i8);
    float4 c = *(const float4*)(X + i8 + 4);
    uint4 o;
    o.x = bf16b(a.x) | (bf16b(a.y) << 16);
    o.y = bf16b(a.z) | (bf16b(a.w) << 16);
    o.z = bf16b(c.x) | (bf16b(c.y) << 16);
    o.w = bf16b(c.z) | (bf16b(c.w) << 16);
    *(uint4*)(Xbf + i8) = o;
  } else {
    const size_t i8 = ((size_t)(b - XCVT_BLOCKS) * 256 + threadIdx.x) * 8;
    int4 p = *(const int4*)(PW + i8);
    int4 q = *(const int4*)(PW + i8 + 4);
    uint2 o;
    o.x = (unsigned)(p.x & 255) | ((unsigned)(p.y & 255) << 8) |
          ((unsigned)(p.z & 255) << 16) | ((unsigned)(p.w & 255) << 24);
    o.y = (unsigned)(q.x & 255) | ((unsigned)(q.y & 255) << 8) |
          ((unsigned)(q.z & 255) << 16) | ((unsigned)(q.w & 255) << 24);
    *(uint2*)(Bt + i8) = o;
  }
}

// ---------------- main MFMA GEMM (A bf16 from ws, B tight-packed from ws) ----
__global__ __launch_bounds__(256, 4)
void qlin_main_kernel(const unsigned short* __restrict__ Xbf,
                      const unsigned char* __restrict__ Bt,
                      const float* __restrict__ SC, float* __restrict__ OUT) {
  __shared__ unsigned short As[2][BM * BK];   // 2 x 16 KB dbuf, 128B rows
  __shared__ unsigned char  Bs[2][BN * 16];   // 2 x 2 KB dbuf, packed, linear
  __shared__ unsigned char  Bdummy[2048];     // waves 2-3 staging sink

  const int tid = threadIdx.x;
  const int lane = tid & 63;
  const int w = tid >> 6;

  const int wg = blockIdx.x;
  const int swz = (wg & 7) * (NWG / 8) + (wg >> 3);
  const int bm = swz / NB_N;
  const int bn = swz - bm * NB_N;

  const int wr = w >> 1;   // 0..1 (M half)
  const int wc = w & 1;    // 0..1 (N half)

  // ---- A stage (identical map to R7): 4 gload_lds/thread, wave region 4KB.
  // LDS o = w*4096 + i*1024 + lane*16 -> row = w*32+i*8+(lane>>3), slot=lane&7.
  // Source chunk c = slot ^ (row&7); row&7 == lane>>3 (m173 pre-swizzled src).
  const int l3 = lane >> 3;
  const char* ab0 = (const char*)Xbf +
      (size_t)(bm * BM + w * 32 + l3) * (K_DIM * 2) + ((lane & 7) ^ l3) * 16;
  // ---- B stage: waves 0-1 real rows (w*64+lane), waves 2-3 same data -> dummy.
  const char* bb = (const char*)Bt +
      (size_t)(bn * BN + (w & 1) * 64 + lane) * (K_DIM / 4);
  unsigned char* bd0 = (w < 2) ? &Bs[0][w * 1024] : &Bdummy[(w - 2) * 1024];
  unsigned char* bd1 = (w < 2) ? &Bs[1][w * 1024] : &Bdummy[(w - 2) * 1024];

#define STAGE(IDX, KT_) do {                                           \
    unsigned short* ad_ = &As[IDX][w * 2048];                          \
    gload_lds16(ab0 + (KT_)*128,           ad_);                       \
    gload_lds16(ab0 + (KT_)*128 + 65536,   ad_ + 512);                 \
    gload_lds16(ab0 + (KT_)*128 + 131072,  ad_ + 1024);                \
    gload_lds16(ab0 + (KT_)*128 + 196608,  ad_ + 1536);                \
    gload_lds16(bb  + (KT_)*16,  (IDX) ? bd1 : bd0);                   \
  } while (0)

  f32x4 acc[4][4];
#pragma unroll
  for (int i = 0; i < 4; ++i)
#pragma unroll
    for (int j = 0; j < 4; ++j) acc[i][j] = (f32x4){0.f, 0.f, 0.f, 0.f};

  // ---- fragment read geometry ----
  const int l4 = lane >> 4;                       // 0..3
  const int axor = lane & 7;                      // A chunk XOR
  const int abase = wr * 8192 + (lane & 15) * 128;  // A byte base (row part)
  const int hb = l4 >> 1;                         // B dword select
  const unsigned hoff = (unsigned)(l4 & 1) * 16;  // B 16-bit half select
  const int rbase = (wc * 64 + (lane & 15)) * 16 + hb * 4;

#define COMPUTE(B_) do {                                                        \
    const char* asb_ = (const char*)&As[B_][0];                                 \
    const unsigned char* bsb_ = &Bs[B_][0];                                     \
    _Pragma("unroll")                                                           \
    for (int kk = 0; kk < 2; ++kk) {                                            \
      bf16x8 af[4];                                                             \
      _Pragma("unroll")                                                         \
      for (int m = 0; m < 4; ++m)                                               \
        af[m] = *(const bf16x8*)(asb_ + abase + m * 2048 +                      \
                                 (((kk * 4 + l4) ^ axor) << 4));                \
      _Pragma("unroll")                                                         \
      for (int n = 0; n < 4; ++n) {                                             \
        const unsigned d = *(const unsigned*)(bsb_ + rbase + n * 256 + kk * 8); \
        const unsigned w16 = (d >> hoff) & 0xFFFFu;                             \
        const unsigned u = w16 | (w16 << 14);                                   \
        union { uint4 s; bf16x8 v; } bfr;                                       \
        bfr.s.x = ((u << 14) & 0xC000C000u) + 0x40004000u;                      \
        bfr.s.y = ((u << 10) & 0xC000C000u) + 0x40004000u;                      \
        bfr.s.z = ((u << 6)  & 0xC000C000u) + 0x40004000u;                      \
        bfr.s.w = ((u << 2)  & 0xC000C000u) + 0x40004000u;                      \
        _Pragma("unroll")                                                       \
        for (int m = 0; m < 4; ++m)                                             \
          acc[m][n] = __builtin_amdgcn_mfma_f32_16x16x32_bf16(af[m], bfr.v,     \
                                                              acc[m][n], 0, 0, 0); \
      }                                                                         \
    }                                                                           \
  } while (0)

  // ---- main loop: double buffer, counted vmcnt(5), 2 raw barriers per kt ----
  STAGE(0, 0);                                   // 5 loads in flight
  int cur = 0;
  for (int kt = 0; kt < KT - 1; ++kt) {
    STAGE(cur ^ 1, kt + 1);                      // 10 in flight
    asm volatile("s_waitcnt vmcnt(5)" ::: "memory");   // cur's 5 done; nxt's fly
    __builtin_amdgcn_s_barrier();                // all waves: cur ready
    __builtin_amdgcn_s_setprio(1);
    COMPUTE(cur);
    __builtin_amdgcn_s_setprio(0);
    asm volatile("s_waitcnt lgkmcnt(0)" ::: "memory"); // my reads of cur done
    __builtin_amdgcn_s_barrier();                // all waves done reading cur
    cur ^= 1;
  }
  asm volatile("s_waitcnt vmcnt(0)" ::: "memory");     // tail: last buffer
  __builtin_amdgcn_s_barrier();
  COMPUTE(cur);
#undef STAGE
#undef COMPUTE

  // ---- epilogue: acc * (-0.5*scale[col]); C/D: col=lane&15, row=(lane>>4)*4+r
  const int gc0 = bn * BN + wc * 64 + (lane & 15);
  const int gr0 = bm * BM + wr * 64 + (l4 << 2);
  float sc[4];
#pragma unroll
  for (int n = 0; n < 4; ++n) sc[n] = -0.5f * SC[gc0 + n * 16];
#pragma unroll
  for (int m = 0; m < 4; ++m)
#pragma unroll
    for (int n = 0; n < 4; ++n)
#pragma unroll
      for (int r = 0; r < 4; ++r)
        OUT[(size_t)(gr0 + m * 16 + r) * N_DIM + gc0 + n * 16] = acc[m][n][r] * sc[n];
}

// ---------------- fallback: R5 fused kernel, 128x256 tile (ws too small) ----
#define FB_BN 256
#define FB_NBN 43
#define FB_NWG 2752
#define BSTRIDE 20
__global__ __launch_bounds__(256, 2)
void qlin_fused_kernel(const float* __restrict__ X, const int* __restrict__ PW,
                       const float* __restrict__ SC, float* __restrict__ OUT) {
  __shared__ unsigned short Asf[BM * BK];
  __shared__ unsigned char Bp[FB_BN * BSTRIDE];

  const int tid = threadIdx.x;
  const int wg = blockIdx.x;
  const int swz = (wg & 7) * (FB_NWG / 8) + (wg >> 3);
  const int bm = swz / FB_NBN;
  const int bn = swz - bm * FB_NBN;

  const int lane = tid & 63;
  const int wave = tid >> 6;
  const int wr = wave >> 1;
  const int wc = wave & 1;

  const int arow = tid >> 3;
  const int ac8  = tid & 7;
  const float* xptr = X + (size_t)(bm * BM + arow) * K_DIM + ac8 * 8;
  const unsigned int aswz = ((unsigned)arow & 7u) << 4;

  const int bc  = tid & 3;
  const int br0 = tid >> 2;
  const int* pwptr = PW + (size_t)(bn * FB_BN + br0) * (K_DIM / 4) + bc * 4;
  const int bwoff = (bc & 1) * 8 + (bc >> 1) * 2;

  f32x4 acc[4][8];
#pragma unroll
  for (int i = 0; i < 4; ++i)
#pragma unroll
    for (int j = 0; j < 8; ++j) acc[i][j] = (f32x4){0.f, 0.f, 0.f, 0.f};

  float4 av[4][2];
  int4 bv[4];
#pragma unroll
  for (int j = 0; j < 4; ++j) {
    av[j][0] = *(const float4*)(xptr + (size_t)(32 * j) * K_DIM);
    av[j][1] = *(const float4*)(xptr + (size_t)(32 * j) * K_DIM + 4);
  }
#pragma unroll
  for (int j = 0; j < 4; ++j)
    bv[j] = *(const int4*)(pwptr + (size_t)(64 * j) * (K_DIM / 4));

  for (int kt = 0; kt < KT; ++kt) {
    __syncthreads();
#pragma unroll
    for (int j = 0; j < 4; ++j) {
      uint4 wv;
      wv.x = bf16b(av[j][0].x) | (bf16b(av[j][0].y) << 16);
      wv.y = bf16b(av[j][0].z) | (bf16b(av[j][0].w) << 16);
      wv.z = bf16b(av[j][1].x) | (bf16b(av[j][1].y) << 16);
      wv.w = bf16b(av[j][1].z) | (bf16b(av[j][1].w) << 16);
      *(uint4*)((char*)Asf + (arow + 32 * j) * 128 + (((unsigned)ac8 * 16u) ^ aswz)) = wv;
    }
#pragma unroll
    for (int j = 0; j < 4; ++j) {
      const unsigned int ulo = ((unsigned)bv[j].x & 255u) | (((unsigned)bv[j].y & 255u) << 8);
      const unsigned int uhi = ((unsigned)bv[j].z & 255u) | (((unsigned)bv[j].w & 255u) << 8);
      unsigned char* dst = Bp + (br0 + 64 * j) * BSTRIDE + bwoff;
      *(unsigned short*)(dst)     = (unsigned short)ulo;
      *(unsigned short*)(dst + 4) = (unsigned short)uhi;
    }
    __syncthreads();

    if (kt + 1 < KT) {
#pragma unroll
      for (int j = 0; j < 4; ++j) {
        av[j][0] = *(const float4*)(xptr + (kt + 1) * BK + (size_t)(32 * j) * K_DIM);
        av[j][1] = *(const float4*)(xptr + (kt + 1) * BK + (size_t)(32 * j) * K_DIM + 4);
      }
#pragma unroll
      for (int j = 0; j < 4; ++j)
        bv[j] = *(const int4*)(pwptr + (kt + 1) * 16 + (size_t)(64 * j) * (K_DIM / 4));
    }

    const int bh = lane >> 4;
    const int bcol0 = wc * 128 + (lane & 15);
    unsigned int d[8];
#pragma unroll
    for (int n = 0; n < 8; ++n)
      d[n] = *(const unsigned int*)(Bp + (bcol0 + n * 16) * BSTRIDE + bh * 4);

    const unsigned int rswz = ((unsigned)lane & 7u) << 4;
#pragma unroll
    for (int kk = 0; kk < 2; ++kk) {
      bf16x8 af[4];
      const unsigned int coff = (((unsigned)(kk * 4 + (lane >> 4))) * 16u) ^ rswz;
#pragma unroll
      for (int m = 0; m < 4; ++m)
        af[m] = *(const bf16x8*)((const char*)Asf + (wr * 64 + m * 16 + (lane & 15)) * 128 + coff);
#pragma unroll
      for (int n = 0; n < 8; ++n) {
        const unsigned int w16 = kk ? (d[n] >> 16) : (d[n] & 0xFFFFu);
        const unsigned int u = w16 | (w16 << 14);
        union { uint4 s; bf16x8 v; } bfr;
        bfr.s.x = ((u << 14) & 0xC000C000u) + 0x40004000u;
        bfr.s.y = ((u << 10) & 0xC000C000u) + 0x40004000u;
        bfr.s.z = ((u << 6)  & 0xC000C000u) + 0x40004000u;
        bfr.s.w = ((u << 2)  & 0xC000C000u) + 0x40004000u;
#pragma unroll
        for (int m = 0; m < 4; ++m)
          acc[m][n] = __builtin_amdgcn_mfma_f32_16x16x32_bf16(af[m], bfr.v, acc[m][n], 0, 0, 0);
      }
    }
  }

  const int gc0 = bn * FB_BN + wc * 128 + (lane & 15);
  const int gr0 = bm * BM + wr * 64 + ((lane >> 4) << 2);
  float sc[8];
#pragma unroll
  for (int n = 0; n < 8; ++n) sc[n] = -0.5f * SC[gc0 + n * 16];
#pragma unroll
  for (int m = 0; m < 4; ++m)
#pragma unroll
    for (int n = 0; n < 8; ++n)
#pragma unroll
      for (int r = 0; r < 4; ++r)
        OUT[(size_t)(gr0 + m * 16 + r) * N_DIM + gc0 + n * 16] = acc[m][n][r] * sc[n];
}

extern "C" void kernel_launch(void* const* d_in, const int* in_sizes, int n_in,
                              void* d_out, int out_size, void* d_ws, size_t ws_size,
                              hipStream_t stream) {
  const float* x  = (const float*)d_in[0];
  const int*   pw = (const int*)d_in[1];
  const float* sc = (const float*)d_in[2];
  float* out = (float*)d_out;
  (void)in_sizes; (void)n_in; (void)out_size;

  if (ws_size >= WS_NEED) {
    unsigned short* xbf = (unsigned short*)d_ws;
    unsigned char* bt = (unsigned char*)d_ws + XBF_BYTES;
    prep_kernel<<<dim3(XCVT_BLOCKS + PACK_BLOCKS), dim3(256), 0, stream>>>(x, pw, xbf, bt);
    qlin_main_kernel<<<dim3(NWG), dim3(256), 0, stream>>>(xbf, bt, sc, out);
  } else {
    qlin_fused_kernel<<<dim3(FB_NWG), dim3(256), 0, stream>>>(x, pw, sc, out);
  }
}

// Round 12
// 733.655 us; speedup vs baseline: 10.4043x; 1.0119x over previous
//
#include <hip/hip_runtime.h>
#include <hip/hip_bf16.h>

// Ternary-quantized linear: out[M,N] = x[M,K] . W^T,  W[n,k] = q[n,k]*scale[n].
// R10: byte-expanded B + v_perm unpack (4 VALU/frag vs 14-op SWAR), R9 4-wave
//      occupancy shape (block 128x128, wave 64x64, acc 64). Pre-pass writes B
//      as per-(bn,kt) LDS tile images with slot swizzle p = s^(row&7) so
//      global_load_lds stays linear and reads XOR (rule 21). Encoding: byte =
//      bf16-high-byte of q -> short b<<8 = q/2 exact; epilogue scale x2.
//      dbuf + counted vmcnt(6) + 2 raw barriers + setprio. launch_bounds(256,3).
//      Tiers: ws>=107MB new path; >=75MB exact R7 path; else fused R5.
// R11/R12: identical resubmits (R10/R11 benches died to infra:
//      UnresponsiveContainer, same pod both times; kernel never measured).

#define M_DIM 8192
#define N_DIM 11008
#define K_DIM 4096
#define BM 128
#define BN 128
#define BK 64
#define KT 64
#define NB_N (N_DIM / BN)          // 86
#define NWG ((M_DIM / BM) * NB_N)  // 5504, %8 == 0

#define XBF_BYTES ((size_t)M_DIM * K_DIM * 2)        // 67108864
#define BEXP_BYTES ((size_t)N_DIM * K_DIM)           // 45088768
#define BT_BYTES  ((size_t)N_DIM * K_DIM / 4)        // 11272192
#define WS1_NEED  (XBF_BYTES + BEXP_BYTES)           // 112197632
#define WS2_NEED  (XBF_BYTES + BT_BYTES)             // 78381056

typedef __attribute__((ext_vector_type(8))) short bf16x8;
typedef __attribute__((ext_vector_type(4))) float f32x4;

__device__ inline unsigned int bf16b(float f) {
  union { __hip_bfloat16 h; unsigned short u; } cv;
  cv.h = __float2bfloat16(f);
  return (unsigned int)cv.u;
}

__device__ __forceinline__ void gload_lds16(const void* g, void* l) {
  __builtin_amdgcn_global_load_lds(
      (const __attribute__((address_space(1))) unsigned int*)g,
      (__attribute__((address_space(3))) unsigned int*)l, 16, 0, 0);
}

#if __has_builtin(__builtin_amdgcn_perm)
#define PERM0(R) __builtin_amdgcn_perm(0u, (R), 0x01040004u)
#define PERM1(R) __builtin_amdgcn_perm(0u, (R), 0x03040204u)
#else
#define PERM0(R) ((((R) & 0x000000FFu) << 8) | (((R) & 0x0000FF00u) << 16))
#define PERM1(R) ((((R) & 0x00FF0000u) >> 8) | ((R) & 0xFF000000u))
#endif

// ---------------- pre-pass kernels ----------------
#define XCVT_BLOCKS 16384   // 16384*256*8 = 33554432 floats
__global__ __launch_bounds__(256)
void xcvt_kernel(const float* __restrict__ X, unsigned short* __restrict__ Xbf) {
  const size_t i8 = ((size_t)blockIdx.x * 256 + threadIdx.x) * 8;
  float4 a = *(const float4*)(X + i8);
  float4 c = *(const float4*)(X + i8 + 4);
  uint4 o;
  o.x = bf16b(a.x) | (bf16b(a.y) << 16);
  o.y = bf16b(a.z) | (bf16b(a.w) << 16);
  o.z = bf16b(c.x) | (bf16b(c.y) << 16);
  o.w = bf16b(c.z) | (bf16b(c.w) << 16);
  *(uint4*)(Xbf + i8) = o;
}

// expand packed byte (4 weights) -> dword of bytes {0xBF(q=-1),0x00,0x3F(q=+1)}
__device__ inline unsigned expb(unsigned e) {
  unsigned o = 0;
#pragma unroll
  for (int j = 0; j < 4; ++j) {
    unsigned t = (e >> (2 * j)) & 3u;
    unsigned f = (t == 0u) ? 0xBFu : ((t == 2u) ? 0x3Fu : 0u);
    o |= f << (8 * j);
  }
  return o;
}

// B byte-expand into per-(bn,kt) LDS tile images [86][64][128 rows][64 B],
// slot s (8 weights) stored at byte offset (s ^ (row&7))*8  (read-XOR match).
#define BEXP_BLOCKS 2752    // 2752*256 = 704512 = 86*64*128 row-tiles
__global__ __launch_bounds__(256)
void bexp_kernel(const int* __restrict__ PW, unsigned char* __restrict__ Bt) {
  const int ti = blockIdx.x * 256 + threadIdx.x;
  const int row = ti & 127;
  const int kt  = (ti >> 7) & 63;
  const int bn  = ti >> 13;
  const int n   = bn * BN + row;
  const int r7  = row & 7;
  const int* src = PW + (size_t)n * (K_DIM / 4) + kt * 16;
  unsigned char* outb = Bt + (size_t)ti * 64;
  int4 v0 = *(const int4*)(src);
  int4 v1 = *(const int4*)(src + 4);
  int4 v2 = *(const int4*)(src + 8);
  int4 v3 = *(const int4*)(src + 12);
  unsigned d[16];
  d[0]=expb((unsigned)v0.x); d[1]=expb((unsigned)v0.y); d[2]=expb((unsigned)v0.z); d[3]=expb((unsigned)v0.w);
  d[4]=expb((unsigned)v1.x); d[5]=expb((unsigned)v1.y); d[6]=expb((unsigned)v1.z); d[7]=expb((unsigned)v1.w);
  d[8]=expb((unsigned)v2.x); d[9]=expb((unsigned)v2.y); d[10]=expb((unsigned)v2.z); d[11]=expb((unsigned)v2.w);
  d[12]=expb((unsigned)v3.x); d[13]=expb((unsigned)v3.y); d[14]=expb((unsigned)v3.z); d[15]=expb((unsigned)v3.w);
  const int sw = r7 & 1;
#pragma unroll
  for (int i = 0; i < 4; ++i) {
    // slots 2i (dwords d[4i],d[4i+1]) and 2i+1 (d[4i+2],d[4i+3])
    uint4 u = sw ? make_uint4(d[4*i+2], d[4*i+3], d[4*i+0], d[4*i+1])
                 : make_uint4(d[4*i+0], d[4*i+1], d[4*i+2], d[4*i+3]);
    *(uint4*)(outb + ((2 * i) ^ (r7 & 6)) * 8) = u;
  }
}

// tier-2 prep: PW one-byte-per-int32 -> tight bytes (row-major packed)
#define PACK_BLOCKS 5504
__global__ __launch_bounds__(256)
void btight_kernel(const int* __restrict__ PW, unsigned char* __restrict__ Bt) {
  const size_t i8 = ((size_t)blockIdx.x * 256 + threadIdx.x) * 8;
  int4 p = *(const int4*)(PW + i8);
  int4 q = *(const int4*)(PW + i8 + 4);
  uint2 o;
  o.x = (unsigned)(p.x & 255) | ((unsigned)(p.y & 255) << 8) |
        ((unsigned)(p.z & 255) << 16) | ((unsigned)(p.w & 255) << 24);
  o.y = (unsigned)(q.x & 255) | ((unsigned)(q.y & 255) << 8) |
        ((unsigned)(q.z & 255) << 16) | ((unsigned)(q.w & 255) << 24);
  *(uint2*)(Bt + i8) = o;
}

// ---------------- tier-1 main: byte-B + perm unpack, 128x128, 4 waves ----
__global__ __launch_bounds__(256, 3)
void qlin_v2_kernel(const unsigned short* __restrict__ Xbf,
                    const unsigned char* __restrict__ Bt,
                    const float* __restrict__ SC, float* __restrict__ OUT) {
  __shared__ unsigned short As[2][BM * BK];   // 2 x 16 KB
  __shared__ unsigned char  Bb[2][BN * BK];   // 2 x 8 KB byte-B

  const int tid = threadIdx.x;
  const int lane = tid & 63;
  const int w = tid >> 6;

  const int wg = blockIdx.x;
  const int swz = (wg & 7) * (NWG / 8) + (wg >> 3);
  const int bm = swz / NB_N;
  const int bn = swz - bm * NB_N;

  const int wr = w >> 1;   // 0..1 (M half)
  const int wc = w & 1;    // 0..1 (N half)

  // A stage (R7-verified map): 4 gload_lds/thread, pre-swizzled source chunks.
  const int l3 = lane >> 3;
  const char* ab0 = (const char*)Xbf +
      (size_t)(bm * BM + w * 32 + l3) * (K_DIM * 2) + ((lane & 7) ^ l3) * 16;
  // B stage: linear copy of prep tile image [bn][kt][128][64]
  const char* bt0 = (const char*)Bt + ((size_t)bn * KT) * 8192;

#define STAGE(IDX, KT_) do {                                           \
    unsigned short* ad_ = &As[IDX][w * 2048];                          \
    gload_lds16(ab0 + (KT_)*128,           ad_);                       \
    gload_lds16(ab0 + (KT_)*128 + 65536,   ad_ + 512);                 \
    gload_lds16(ab0 + (KT_)*128 + 131072,  ad_ + 1024);                \
    gload_lds16(ab0 + (KT_)*128 + 196608,  ad_ + 1536);                \
    const char* bg_ = bt0 + (size_t)(KT_)*8192 + w * 2048 + lane * 16; \
    unsigned char* bd_ = &Bb[IDX][w * 2048];                           \
    gload_lds16(bg_,          bd_);                                    \
    gload_lds16(bg_ + 1024,   bd_ + 1024);                             \
  } while (0)

  f32x4 acc[4][4];
#pragma unroll
  for (int i = 0; i < 4; ++i)
#pragma unroll
    for (int j = 0; j < 4; ++j) acc[i][j] = (f32x4){0.f, 0.f, 0.f, 0.f};

  const int l4 = lane >> 4;
  const int l7 = lane & 7;
  const int abyte = (wr * 64 + (lane & 15)) * 128;  // + m*2048 + chunk
  const int bbyte = (wc * 64 + (lane & 15)) * 64;   // + n*1024 + slot

#define COMPUTE(B_) do {                                                        \
    const char* asb_ = (const char*)&As[B_][0];                                 \
    const char* bsb_ = (const char*)&Bb[B_][0];                                 \
    _Pragma("unroll")                                                           \
    for (int kk = 0; kk < 2; ++kk) {                                            \
      const int cx_ = (kk * 4 + l4) ^ l7;                                       \
      bf16x8 af[4];                                                             \
      _Pragma("unroll")                                                         \
      for (int m = 0; m < 4; ++m)                                               \
        af[m] = *(const bf16x8*)(asb_ + abyte + m * 2048 + (cx_ << 4));         \
      _Pragma("unroll")                                                         \
      for (int n = 0; n < 4; ++n) {                                             \
        const uint2 rv = *(const uint2*)(bsb_ + bbyte + n * 1024 + (cx_ << 3)); \
        union { uint4 s; bf16x8 v; } bfr;                                       \
        bfr.s.x = PERM0(rv.x);                                                  \
        bfr.s.y = PERM1(rv.x);                                                  \
        bfr.s.z = PERM0(rv.y);                                                  \
        bfr.s.w = PERM1(rv.y);                                                  \
        _Pragma("unroll")                                                       \
        for (int m = 0; m < 4; ++m)                                             \
          acc[m][n] = __builtin_amdgcn_mfma_f32_16x16x32_bf16(af[m], bfr.v,     \
                                                              acc[m][n], 0, 0, 0); \
      }                                                                         \
    }                                                                           \
  } while (0)

  STAGE(0, 0);                                   // 6 loads in flight
  int cur = 0;
  for (int kt = 0; kt < KT - 1; ++kt) {
    STAGE(cur ^ 1, kt + 1);                      // 12 in flight
    asm volatile("s_waitcnt vmcnt(6)" ::: "memory");   // cur's 6 done; nxt's fly
    __builtin_amdgcn_s_barrier();
    __builtin_amdgcn_s_setprio(1);
    COMPUTE(cur);
    __builtin_amdgcn_s_setprio(0);
    asm volatile("s_waitcnt lgkmcnt(0)" ::: "memory");
    __builtin_amdgcn_s_barrier();
    cur ^= 1;
  }
  asm volatile("s_waitcnt vmcnt(0)" ::: "memory");
  __builtin_amdgcn_s_barrier();
  COMPUTE(cur);
#undef STAGE
#undef COMPUTE

  // epilogue: W held = q/2 -> scale by 2*SC. C/D: col=lane&15, row=(lane>>4)*4+r
  const int gc0 = bn * BN + wc * 64 + (lane & 15);
  const int gr0 = bm * BM + wr * 64 + (l4 << 2);
  float sc[4];
#pragma unroll
  for (int n = 0; n < 4; ++n) sc[n] = 2.0f * SC[gc0 + n * 16];
#pragma unroll
  for (int m = 0; m < 4; ++m)
#pragma unroll
    for (int n = 0; n < 4; ++n)
#pragma unroll
      for (int r = 0; r < 4; ++r)
        OUT[(size_t)(gr0 + m * 16 + r) * N_DIM + gc0 + n * 16] = acc[m][n][r] * sc[n];
}

// ---------------- tier-2 main: exact R7 kernel (packed-B SWAR, 128x256) ----
__global__ __launch_bounds__(256, 2)
void qlin_r7_kernel(const unsigned short* __restrict__ Xbf,
                    const unsigned char* __restrict__ Bt,
                    const float* __restrict__ SC, float* __restrict__ OUT) {
  __shared__ unsigned short As[3][128 * 64];
  __shared__ unsigned char  Bs[3][256 * 16];

  const int tid = threadIdx.x;
  const int lane = tid & 63;
  const int w = tid >> 6;

  const int wg = blockIdx.x;
  const int swz = (wg & 7) * (2752 / 8) + (wg >> 3);
  const int bm = swz / 43;
  const int bn = swz - bm * 43;

  const int l3 = lane >> 3;
  const char* ab0 = (const char*)Xbf +
      (size_t)(bm * 128 + w * 32 + l3) * (K_DIM * 2) + ((lane & 7) ^ l3) * 16;
  const char* bb = (const char*)Bt + (size_t)(bn * 256 + w * 64 + lane) * (K_DIM / 4);

#define STAGE(IDX, KT_) do {                                           \
    unsigned short* ad_ = &As[IDX][w * 2048];                          \
    unsigned char* bd_ = &Bs[IDX][w * 1024];                           \
    gload_lds16(ab0 + (KT_)*128,           ad_);                       \
    gload_lds16(ab0 + (KT_)*128 + 65536,   ad_ + 512);                 \
    gload_lds16(ab0 + (KT_)*128 + 131072,  ad_ + 1024);                \
    gload_lds16(ab0 + (KT_)*128 + 196608,  ad_ + 1536);                \
    gload_lds16(bb  + (KT_)*16,            bd_);                       \
  } while (0)

  f32x4 acc[8][4];
#pragma unroll
  for (int i = 0; i < 8; ++i)
#pragma unroll
    for (int j = 0; j < 4; ++j) acc[i][j] = (f32x4){0.f, 0.f, 0.f, 0.f};

  const int l4 = lane >> 4;
  const int axor = lane & 7;
  const int arow = (lane & 15) * 128;
  const int hb = l4 >> 1;
  const unsigned hoff = (unsigned)(l4 & 1) * 16;
  const int rbase = (w * 64 + (lane & 15)) * 16 + hb * 4;

#define COMPUTE(B_) do {                                                        \
    const char* asb_ = (const char*)&As[B_][0];                                 \
    const unsigned char* bsb_ = &Bs[B_][0];                                     \
    _Pragma("unroll")                                                           \
    for (int kk = 0; kk < 2; ++kk) {                                            \
      bf16x8 af[8];                                                             \
      _Pragma("unroll")                                                         \
      for (int m = 0; m < 8; ++m)                                               \
        af[m] = *(const bf16x8*)(asb_ + m * 2048 + arow +                       \
                                 (((kk * 4 + l4) ^ axor) << 4));                \
      _Pragma("unroll")                                                         \
      for (int n = 0; n < 4; ++n) {                                             \
        const unsigned d = *(const unsigned*)(bsb_ + rbase + n * 256 + kk * 8); \
        const unsigned w16 = (d >> hoff) & 0xFFFFu;                             \
        const unsigned u = w16 | (w16 << 14);                                   \
        union { uint4 s; bf16x8 v; } bfr;                                       \
        bfr.s.x = ((u << 14) & 0xC000C000u) + 0x40004000u;                      \
        bfr.s.y = ((u << 10) & 0xC000C000u) + 0x40004000u;                      \
        bfr.s.z = ((u << 6)  & 0xC000C000u) + 0x40004000u;                      \
        bfr.s.w = ((u << 2)  & 0xC000C000u) + 0x40004000u;                      \
        _Pragma("unroll")                                                       \
        for (int m = 0; m < 8; ++m)                                             \
          acc[m][n] = __builtin_amdgcn_mfma_f32_16x16x32_bf16(af[m], bfr.v,     \
                                                              acc[m][n], 0, 0, 0); \
      }                                                                         \
    }                                                                           \
  } while (0)

  STAGE(0, 0);
  int cur = 0;
  for (int kt = 0; kt < KT - 1; ++kt) {
    const int nxt = (cur == 2) ? 0 : cur + 1;
    STAGE(nxt, kt + 1);
    asm volatile("s_waitcnt vmcnt(5)" ::: "memory");
    asm volatile("s_waitcnt lgkmcnt(0)" ::: "memory");
    __builtin_amdgcn_s_barrier();
    COMPUTE(cur);
    cur = nxt;
  }
  asm volatile("s_waitcnt vmcnt(0)" ::: "memory");
  asm volatile("s_waitcnt lgkmcnt(0)" ::: "memory");
  __builtin_amdgcn_s_barrier();
  COMPUTE(cur);
#undef STAGE
#undef COMPUTE

  const int gc0 = bn * 256 + w * 64 + (lane & 15);
  const int gr0 = bm * 128 + (l4 << 2);
  float sc[4];
#pragma unroll
  for (int n = 0; n < 4; ++n) sc[n] = -0.5f * SC[gc0 + n * 16];
#pragma unroll
  for (int m = 0; m < 8; ++m)
#pragma unroll
    for (int n = 0; n < 4; ++n)
#pragma unroll
      for (int r = 0; r < 4; ++r)
        OUT[(size_t)(gr0 + m * 16 + r) * N_DIM + gc0 + n * 16] = acc[m][n][r] * sc[n];
}

// ---------------- tier-3 fallback: R5 fused kernel ----------
#define BSTRIDE 20
__global__ __launch_bounds__(256, 2)
void qlin_fused_kernel(const float* __restrict__ X, const int* __restrict__ PW,
                       const float* __restrict__ SC, float* __restrict__ OUT) {
  __shared__ unsigned short Asf[128 * 64];
  __shared__ unsigned char Bp[256 * BSTRIDE];

  const int tid = threadIdx.x;
  const int wg = blockIdx.x;
  const int swz = (wg & 7) * (2752 / 8) + (wg >> 3);
  const int bm = swz / 43;
  const int bn = swz - bm * 43;

  const int lane = tid & 63;
  const int wave = tid >> 6;
  const int wr = wave >> 1;
  const int wc = wave & 1;

  const int arow = tid >> 3;
  const int ac8  = tid & 7;
  const float* xptr = X + (size_t)(bm * 128 + arow) * K_DIM + ac8 * 8;
  const unsigned int aswz = ((unsigned)arow & 7u) << 4;

  const int bc  = tid & 3;
  const int br0 = tid >> 2;
  const int* pwptr = PW + (size_t)(bn * 256 + br0) * (K_DIM / 4) + bc * 4;
  const int bwoff = (bc & 1) * 8 + (bc >> 1) * 2;

  f32x4 acc[4][8];
#pragma unroll
  for (int i = 0; i < 4; ++i)
#pragma unroll
    for (int j = 0; j < 8; ++j) acc[i][j] = (f32x4){0.f, 0.f, 0.f, 0.f};

  float4 av[4][2];
  int4 bv[4];
#pragma unroll
  for (int j = 0; j < 4; ++j) {
    av[j][0] = *(const float4*)(xptr + (size_t)(32 * j) * K_DIM);
    av[j][1] = *(const float4*)(xptr + (size_t)(32 * j) * K_DIM + 4);
  }
#pragma unroll
  for (int j = 0; j < 4; ++j)
    bv[j] = *(const int4*)(pwptr + (size_t)(64 * j) * (K_DIM / 4));

  for (int kt = 0; kt < KT; ++kt) {
    __syncthreads();
#pragma unroll
    for (int j = 0; j < 4; ++j) {
      uint4 wv;
      wv.x = bf16b(av[j][0].x) | (bf16b(av[j][0].y) << 16);
      wv.y = bf16b(av[j][0].z) | (bf16b(av[j][0].w) << 16);
      wv.z = bf16b(av[j][1].x) | (bf16b(av[j][1].y) << 16);
      wv.w = bf16b(av[j][1].z) | (bf16b(av[j][1].w) << 16);
      *(uint4*)((char*)Asf + (arow + 32 * j) * 128 + (((unsigned)ac8 * 16u) ^ aswz)) = wv;
    }
#pragma unroll
    for (int j = 0; j < 4; ++j) {
      const unsigned int ulo = ((unsigned)bv[j].x & 255u) | (((unsigned)bv[j].y & 255u) << 8);
      const unsigned int uhi = ((unsigned)bv[j].z & 255u) | (((unsigned)bv[j].w & 255u) << 8);
      unsigned char* dst = Bp + (br0 + 64 * j) * BSTRIDE + bwoff;
      *(unsigned short*)(dst)     = (unsigned short)ulo;
      *(unsigned short*)(dst + 4) = (unsigned short)uhi;
    }
    __syncthreads();

    if (kt + 1 < KT) {
#pragma unroll
      for (int j = 0; j < 4; ++j) {
        av[j][0] = *(const float4*)(xptr + (kt + 1) * BK + (size_t)(32 * j) * K_DIM);
        av[j][1] = *(const float4*)(xptr + (kt + 1) * BK + (size_t)(32 * j) * K_DIM + 4);
      }
#pragma unroll
      for (int j = 0; j < 4; ++j)
        bv[j] = *(const int4*)(pwptr + (kt + 1) * 16 + (size_t)(64 * j) * (K_DIM / 4));
    }

    const int bh = lane >> 4;
    const int bcol0 = wc * 128 + (lane & 15);
    unsigned int d[8];
#pragma unroll
    for (int n = 0; n < 8; ++n)
      d[n] = *(const unsigned int*)(Bp + (bcol0 + n * 16) * BSTRIDE + bh * 4);

    const unsigned int rswz = ((unsigned)lane & 7u) << 4;
#pragma unroll
    for (int kk = 0; kk < 2; ++kk) {
      bf16x8 af[4];
      const unsigned int coff = (((unsigned)(kk * 4 + (lane >> 4))) * 16u) ^ rswz;
#pragma unroll
      for (int m = 0; m < 4; ++m)
        af[m] = *(const bf16x8*)((const char*)Asf + (wr * 64 + m * 16 + (lane & 15)) * 128 + coff);
#pragma unroll
      for (int n = 0; n < 8; ++n) {
        const unsigned int w16 = kk ? (d[n] >> 16) : (d[n] & 0xFFFFu);
        const unsigned int u = w16 | (w16 << 14);
        union { uint4 s; bf16x8 v; } bfr;
        bfr.s.x = ((u << 14) & 0xC000C000u) + 0x40004000u;
        bfr.s.y = ((u << 10) & 0xC000C000u) + 0x40004000u;
        bfr.s.z = ((u << 6)  & 0xC000C000u) + 0x40004000u;
        bfr.s.w = ((u << 2)  & 0xC000C000u) + 0x40004000u;
#pragma unroll
        for (int m = 0; m < 4; ++m)
          acc[m][n] = __builtin_amdgcn_mfma_f32_16x16x32_bf16(af[m], bfr.v, acc[m][n], 0, 0, 0);
      }
    }
  }

  const int gc0 = bn * 256 + wc * 128 + (lane & 15);
  const int gr0 = bm * 128 + wr * 64 + ((lane >> 4) << 2);
  float sc[8];
#pragma unroll
  for (int n = 0; n < 8; ++n) sc[n] = -0.5f * SC[gc0 + n * 16];
#pragma unroll
  for (int m = 0; m < 4; ++m)
#pragma unroll
    for (int n = 0; n < 8; ++n)
#pragma unroll
      for (int r = 0; r < 4; ++r)
        OUT[(size_t)(gr0 + m * 16 + r) * N_DIM + gc0 + n * 16] = acc[m][n][r] * sc[n];
}

extern "C" void kernel_launch(void* const* d_in, const int* in_sizes, int n_in,
                              void* d_out, int out_size, void* d_ws, size_t ws_size,
                              hipStream_t stream) {
  const float* x  = (const float*)d_in[0];
  const int*   pw = (const int*)d_in[1];
  const float* sc = (const float*)d_in[2];
  float* out = (float*)d_out;
  (void)in_sizes; (void)n_in; (void)out_size;

  if (ws_size >= WS1_NEED) {
    unsigned short* xbf = (unsigned short*)d_ws;
    unsigned char* bt = (unsigned char*)d_ws + XBF_BYTES;
    xcvt_kernel<<<dim3(XCVT_BLOCKS), dim3(256), 0, stream>>>(x, xbf);
    bexp_kernel<<<dim3(BEXP_BLOCKS), dim3(256), 0, stream>>>(pw, bt);
    qlin_v2_kernel<<<dim3(NWG), dim3(256), 0, stream>>>(xbf, bt, sc, out);
  } else if (ws_size >= WS2_NEED) {
    unsigned short* xbf = (unsigned short*)d_ws;
    unsigned char* bt = (unsigned char*)d_ws + XBF_BYTES;
    xcvt_kernel<<<dim3(XCVT_BLOCKS), dim3(256), 0, stream>>>(x, xbf);
    btight_kernel<<<dim3(PACK_BLOCKS), dim3(256), 0, stream>>>(pw, bt);
    qlin_r7_kernel<<<dim3(2752), dim3(256), 0, stream>>>(xbf, bt, sc, out);
  } else {
    qlin_fused_kernel<<<dim3(2752), dim3(256), 0, stream>>>(x, pw, sc, out);
  }
}

// Round 13
// 700.061 us; speedup vs baseline: 10.9036x; 1.0480x over previous
//
#include <hip/hip_runtime.h>
#include <hip/hip_bf16.h>

// Ternary-quantized linear: out[M,N] = x[M,K] . W^T,  W[n,k] = q[n,k]*scale[n].
// R13: R7 geometry (best measured: 128x256 block, 4 waves of 128x64, ring-3,
//      counted vmcnt(5), pre-pass x->bf16 + W tight-pack) restructured into a
//      4-phase-per-kt schedule (T3/m196): phase = (kk, m-half), each
//      {4 ds_read_b128 [+4 B b32] ; barrier ; lgkmcnt(0) ; setprio(1) ;
//       [SWAR unpack] ; 16 MFMA ; setprio(0) ; barrier}. STAGE(kt+2) issued in
//      phase 0; vmcnt(5) only at phase 3 (tail: vmcnt(0)). bfr persists across
//      the two m-half phases (unpack stays 1.75 VALU/MFMA). Fallback = R5 fused.

#define M_DIM 8192
#define N_DIM 11008
#define K_DIM 4096
#define BM 128
#define BN 256
#define BK 64
#define KT 64
#define NB_N 43
#define NWG 2752                    // 64*43, %8 == 0

#define XBF_BYTES ((size_t)M_DIM * K_DIM * 2)        // 67108864
#define BT_BYTES  ((size_t)N_DIM * K_DIM / 4)        // 11272192
#define WS_NEED   (XBF_BYTES + BT_BYTES)             // 78381056

typedef __attribute__((ext_vector_type(8))) short bf16x8;
typedef __attribute__((ext_vector_type(4))) float f32x4;

__device__ inline unsigned int bf16b(float f) {
  union { __hip_bfloat16 h; unsigned short u; } cv;
  cv.h = __float2bfloat16(f);
  return (unsigned int)cv.u;
}

__device__ __forceinline__ void gload_lds16(const void* g, void* l) {
  __builtin_amdgcn_global_load_lds(
      (const __attribute__((address_space(1))) unsigned int*)g,
      (__attribute__((address_space(3))) unsigned int*)l, 16, 0, 0);
}

// ---------------- pre-pass: x fp32->bf16 ; PW one-byte-per-int32 -> tight bytes
#define XCVT_BLOCKS 16384   // 16384*256*8 = 33554432 floats
#define PACK_BLOCKS 5504    // 5504*256*8  = 11272192 int32s
__global__ __launch_bounds__(256)
void xcvt_kernel(const float* __restrict__ X, unsigned short* __restrict__ Xbf) {
  const size_t i8 = ((size_t)blockIdx.x * 256 + threadIdx.x) * 8;
  float4 a = *(const float4*)(X + i8);
  float4 c = *(const float4*)(X + i8 + 4);
  uint4 o;
  o.x = bf16b(a.x) | (bf16b(a.y) << 16);
  o.y = bf16b(a.z) | (bf16b(a.w) << 16);
  o.z = bf16b(c.x) | (bf16b(c.y) << 16);
  o.w = bf16b(c.z) | (bf16b(c.w) << 16);
  *(uint4*)(Xbf + i8) = o;
}

__global__ __launch_bounds__(256)
void btight_kernel(const int* __restrict__ PW, unsigned char* __restrict__ Bt) {
  const size_t i8 = ((size_t)blockIdx.x * 256 + threadIdx.x) * 8;
  int4 p = *(const int4*)(PW + i8);
  int4 q = *(const int4*)(PW + i8 + 4);
  uint2 o;
  o.x = (unsigned)(p.x & 255) | ((unsigned)(p.y & 255) << 8) |
        ((unsigned)(p.z & 255) << 16) | ((unsigned)(p.w & 255) << 24);
  o.y = (unsigned)(q.x & 255) | ((unsigned)(q.y & 255) << 8) |
        ((unsigned)(q.z & 255) << 16) | ((unsigned)(q.w & 255) << 24);
  *(uint2*)(Bt + i8) = o;
}

// ---------------- main: R7 geometry, 4-phase schedule ----------------
__global__ __launch_bounds__(256, 2)
void qlin_p4_kernel(const unsigned short* __restrict__ Xbf,
                    const unsigned char* __restrict__ Bt,
                    const float* __restrict__ SC, float* __restrict__ OUT) {
  __shared__ unsigned short As[3][BM * BK];   // 3 x 16 KB ring
  __shared__ unsigned char  Bs[3][BN * 16];   // 3 x 4 KB ring, packed

  const int tid = threadIdx.x;
  const int lane = tid & 63;
  const int w = tid >> 6;

  const int wg = blockIdx.x;
  const int swz = (wg & 7) * (NWG / 8) + (wg >> 3);
  const int bm = swz / NB_N;
  const int bn = swz - bm * NB_N;

  // A stage map (R7-verified): 4 gload_lds/thread, pre-swizzled source chunks.
  const int l3 = lane >> 3;
  const char* ab0 = (const char*)Xbf +
      (size_t)(bm * BM + w * 32 + l3) * (K_DIM * 2) + ((lane & 7) ^ l3) * 16;
  // B stage: 1 gload_lds/wave; row w*64+lane, 16 B per kt.
  const char* bb = (const char*)Bt + (size_t)(bn * BN + w * 64 + lane) * (K_DIM / 4);

#define STAGE(IDX, KT_) do {                                           \
    unsigned short* ad_ = &As[IDX][w * 2048];                          \
    unsigned char* bd_ = &Bs[IDX][w * 1024];                           \
    gload_lds16(ab0 + (KT_)*128,           ad_);                       \
    gload_lds16(ab0 + (KT_)*128 + 65536,   ad_ + 512);                 \
    gload_lds16(ab0 + (KT_)*128 + 131072,  ad_ + 1024);                \
    gload_lds16(ab0 + (KT_)*128 + 196608,  ad_ + 1536);                \
    gload_lds16(bb  + (KT_)*16,            bd_);                       \
  } while (0)

  f32x4 acc[8][4];
#pragma unroll
  for (int i = 0; i < 8; ++i)
#pragma unroll
    for (int j = 0; j < 4; ++j) acc[i][j] = (f32x4){0.f, 0.f, 0.f, 0.f};

  // fragment geometry (R7)
  const int l4 = lane >> 4;
  const int axor = lane & 7;
  const int arow = (lane & 15) * 128;
  const int hb = l4 >> 1;
  const unsigned hoff = (unsigned)(l4 & 1) * 16;
  const int rbase = (w * 64 + (lane & 15)) * 16 + hb * 4;

  bf16x8 af[4];
  bf16x8 bfr[4];
  unsigned d4[4];

#define DSA(CB, KK, H) do {                                                    \
    const char* asb_ = (const char*)&As[CB][0];                                \
    _Pragma("unroll")                                                          \
    for (int m = 0; m < 4; ++m)                                                \
      af[m] = *(const bf16x8*)(asb_ + ((H) * 4 + m) * 2048 + arow +            \
                               ((((KK) * 4 + l4) ^ axor) << 4));               \
  } while (0)

#define DSB(CB, KK) do {                                                       \
    const unsigned char* bsb_ = &Bs[CB][0];                                    \
    _Pragma("unroll")                                                          \
    for (int n = 0; n < 4; ++n)                                                \
      d4[n] = *(const unsigned*)(bsb_ + rbase + n * 256 + (KK) * 8);           \
  } while (0)

#define UNPACK() do {                                                          \
    _Pragma("unroll")                                                          \
    for (int n = 0; n < 4; ++n) {                                              \
      const unsigned w16 = (d4[n] >> hoff) & 0xFFFFu;                          \
      const unsigned u = w16 | (w16 << 14);                                    \
      union { uint4 s; bf16x8 v; } t;                                          \
      t.s.x = ((u << 14) & 0xC000C000u) + 0x40004000u;                         \
      t.s.y = ((u << 10) & 0xC000C000u) + 0x40004000u;                         \
      t.s.z = ((u << 6)  & 0xC000C000u) + 0x40004000u;                         \
      t.s.w = ((u << 2)  & 0xC000C000u) + 0x40004000u;                         \
      bfr[n] = t.v;                                                            \
    }                                                                          \
  } while (0)

#define MFMA16(H) do {                                                         \
    _Pragma("unroll")                                                          \
    for (int m = 0; m < 4; ++m)                                                \
      _Pragma("unroll")                                                        \
      for (int n = 0; n < 4; ++n)                                              \
        acc[(H) * 4 + m][n] = __builtin_amdgcn_mfma_f32_16x16x32_bf16(         \
            af[m], bfr[n], acc[(H) * 4 + m][n], 0, 0, 0);                      \
  } while (0)

#define BAR() __builtin_amdgcn_s_barrier()
#define LGKM0() asm volatile("s_waitcnt lgkmcnt(0)" ::: "memory")
#define PRIO(P) __builtin_amdgcn_s_setprio(P)

  // prologue: buffers 0 and 1 in flight; wait buffer 0 only (counted)
  STAGE(0, 0);
  STAGE(1, 1);
  asm volatile("s_waitcnt vmcnt(5)" ::: "memory");
  BAR();

  int cb = 0, sb = 2;   // current buffer, stage buffer (kt+2)
  for (int kt = 0; kt < KT; ++kt) {
    const bool more = (kt + 2 < KT);
    // ---- phase 0: (kk=0, m-half 0) + stage kt+2 ----
    DSA(cb, 0, 0);
    DSB(cb, 0);
    if (more) STAGE(sb, kt + 2);
    BAR(); LGKM0(); PRIO(1);
    UNPACK();
    MFMA16(0);
    PRIO(0); BAR();
    // ---- phase 1: (kk=0, m-half 1) ----
    DSA(cb, 0, 1);
    BAR(); LGKM0(); PRIO(1);
    MFMA16(1);
    PRIO(0); BAR();
    // ---- phase 2: (kk=1, m-half 0) ----
    DSA(cb, 1, 0);
    DSB(cb, 1);
    BAR(); LGKM0(); PRIO(1);
    UNPACK();
    MFMA16(0);
    PRIO(0); BAR();
    // ---- phase 3: (kk=1, m-half 1) + counted vmcnt for kt+1's buffer ----
    DSA(cb, 1, 1);
    if (more) { asm volatile("s_waitcnt vmcnt(5)" ::: "memory"); }
    else      { asm volatile("s_waitcnt vmcnt(0)" ::: "memory"); }
    BAR(); LGKM0(); PRIO(1);
    MFMA16(1);
    PRIO(0); BAR();
    cb = (cb == 2) ? 0 : cb + 1;
    sb = (sb == 2) ? 0 : sb + 1;
  }
#undef STAGE
#undef DSA
#undef DSB
#undef UNPACK
#undef MFMA16

  // epilogue: acc * (-0.5*scale[col]); C/D: col=lane&15, row=(lane>>4)*4+r
  const int gc0 = bn * BN + w * 64 + (lane & 15);
  const int gr0 = bm * BM + (l4 << 2);
  float sc[4];
#pragma unroll
  for (int n = 0; n < 4; ++n) sc[n] = -0.5f * SC[gc0 + n * 16];
#pragma unroll
  for (int m = 0; m < 8; ++m)
#pragma unroll
    for (int n = 0; n < 4; ++n)
#pragma unroll
      for (int r = 0; r < 4; ++r)
        OUT[(size_t)(gr0 + m * 16 + r) * N_DIM + gc0 + n * 16] = acc[m][n][r] * sc[n];
}

// ---------------- fallback: R5 fused kernel (ws too small) ----------
#define BSTRIDE 20
__global__ __launch_bounds__(256, 2)
void qlin_fused_kernel(const float* __restrict__ X, const int* __restrict__ PW,
                       const float* __restrict__ SC, float* __restrict__ OUT) {
  __shared__ unsigned short Asf[128 * 64];
  __shared__ unsigned char Bp[256 * BSTRIDE];

  const int tid = threadIdx.x;
  const int wg = blockIdx.x;
  const int swz = (wg & 7) * (NWG / 8) + (wg >> 3);
  const int bm = swz / NB_N;
  const int bn = swz - bm * NB_N;

  const int lane = tid & 63;
  const int wave = tid >> 6;
  const int wr = wave >> 1;
  const int wc = wave & 1;

  const int arow = tid >> 3;
  const int ac8  = tid & 7;
  const float* xptr = X + (size_t)(bm * 128 + arow) * K_DIM + ac8 * 8;
  const unsigned int aswz = ((unsigned)arow & 7u) << 4;

  const int bc  = tid & 3;
  const int br0 = tid >> 2;
  const int* pwptr = PW + (size_t)(bn * 256 + br0) * (K_DIM / 4) + bc * 4;
  const int bwoff = (bc & 1) * 8 + (bc >> 1) * 2;

  f32x4 acc[4][8];
#pragma unroll
  for (int i = 0; i < 4; ++i)
#pragma unroll
    for (int j = 0; j < 8; ++j) acc[i][j] = (f32x4){0.f, 0.f, 0.f, 0.f};

  float4 av[4][2];
  int4 bv[4];
#pragma unroll
  for (int j = 0; j < 4; ++j) {
    av[j][0] = *(const float4*)(xptr + (size_t)(32 * j) * K_DIM);
    av[j][1] = *(const float4*)(xptr + (size_t)(32 * j) * K_DIM + 4);
  }
#pragma unroll
  for (int j = 0; j < 4; ++j)
    bv[j] = *(const int4*)(pwptr + (size_t)(64 * j) * (K_DIM / 4));

  for (int kt = 0; kt < KT; ++kt) {
    __syncthreads();
#pragma unroll
    for (int j = 0; j < 4; ++j) {
      uint4 wv;
      wv.x = bf16b(av[j][0].x) | (bf16b(av[j][0].y) << 16);
      wv.y = bf16b(av[j][0].z) | (bf16b(av[j][0].w) << 16);
      wv.z = bf16b(av[j][1].x) | (bf16b(av[j][1].y) << 16);
      wv.w = bf16b(av[j][1].z) | (bf16b(av[j][1].w) << 16);
      *(uint4*)((char*)Asf + (arow + 32 * j) * 128 + (((unsigned)ac8 * 16u) ^ aswz)) = wv;
    }
#pragma unroll
    for (int j = 0; j < 4; ++j) {
      const unsigned int ulo = ((unsigned)bv[j].x & 255u) | (((unsigned)bv[j].y & 255u) << 8);
      const unsigned int uhi = ((unsigned)bv[j].z & 255u) | (((unsigned)bv[j].w & 255u) << 8);
      unsigned char* dst = Bp + (br0 + 64 * j) * BSTRIDE + bwoff;
      *(unsigned short*)(dst)     = (unsigned short)ulo;
      *(unsigned short*)(dst + 4) = (unsigned short)uhi;
    }
    __syncthreads();

    if (kt + 1 < KT) {
#pragma unroll
      for (int j = 0; j < 4; ++j) {
        av[j][0] = *(const float4*)(xptr + (kt + 1) * BK + (size_t)(32 * j) * K_DIM);
        av[j][1] = *(const float4*)(xptr + (kt + 1) * BK + (size_t)(32 * j) * K_DIM + 4);
      }
#pragma unroll
      for (int j = 0; j < 4; ++j)
        bv[j] = *(const int4*)(pwptr + (kt + 1) * 16 + (size_t)(64 * j) * (K_DIM / 4));
    }

    const int bh = lane >> 4;
    const int bcol0 = wc * 128 + (lane & 15);
    unsigned int d[8];
#pragma unroll
    for (int n = 0; n < 8; ++n)
      d[n] = *(const unsigned int*)(Bp + (bcol0 + n * 16) * BSTRIDE + bh * 4);

    const unsigned int rswz = ((unsigned)lane & 7u) << 4;
#pragma unroll
    for (int kk = 0; kk < 2; ++kk) {
      bf16x8 af[4];
      const unsigned int coff = (((unsigned)(kk * 4 + (lane >> 4))) * 16u) ^ rswz;
#pragma unroll
      for (int m = 0; m < 4; ++m)
        af[m] = *(const bf16x8*)((const char*)Asf + (wr * 64 + m * 16 + (lane & 15)) * 128 + coff);
#pragma unroll
      for (int n = 0; n < 8; ++n) {
        const unsigned int w16 = kk ? (d[n] >> 16) : (d[n] & 0xFFFFu);
        const unsigned int u = w16 | (w16 << 14);
        union { uint4 s; bf16x8 v; } bfr;
        bfr.s.x = ((u << 14) & 0xC000C000u) + 0x40004000u;
        bfr.s.y = ((u << 10) & 0xC000C000u) + 0x40004000u;
        bfr.s.z = ((u << 6)  & 0xC000C000u) + 0x40004000u;
        bfr.s.w = ((u << 2)  & 0xC000C000u) + 0x40004000u;
#pragma unroll
        for (int m = 0; m < 4; ++m)
          acc[m][n] = __builtin_amdgcn_mfma_f32_16x16x32_bf16(af[m], bfr.v, acc[m][n], 0, 0, 0);
      }
    }
  }

  const int gc0 = bn * 256 + wc * 128 + (lane & 15);
  const int gr0 = bm * 128 + wr * 64 + ((lane >> 4) << 2);
  float sc[8];
#pragma unroll
  for (int n = 0; n < 8; ++n) sc[n] = -0.5f * SC[gc0 + n * 16];
#pragma unroll
  for (int m = 0; m < 4; ++m)
#pragma unroll
    for (int n = 0; n < 8; ++n)
#pragma unroll
      for (int r = 0; r < 4; ++r)
        OUT[(size_t)(gr0 + m * 16 + r) * N_DIM + gc0 + n * 16] = acc[m][n][r] * sc[n];
}

extern "C" void kernel_launch(void* const* d_in, const int* in_sizes, int n_in,
                              void* d_out, int out_size, void* d_ws, size_t ws_size,
                              hipStream_t stream) {
  const float* x  = (const float*)d_in[0];
  const int*   pw = (const int*)d_in[1];
  const float* sc = (const float*)d_in[2];
  float* out = (float*)d_out;
  (void)in_sizes; (void)n_in; (void)out_size;

  if (ws_size >= WS_NEED) {
    unsigned short* xbf = (unsigned short*)d_ws;
    unsigned char* bt = (unsigned char*)d_ws + XBF_BYTES;
    xcvt_kernel<<<dim3(XCVT_BLOCKS), dim3(256), 0, stream>>>(x, xbf);
    btight_kernel<<<dim3(PACK_BLOCKS), dim3(256), 0, stream>>>(pw, bt);
    qlin_p4_kernel<<<dim3(NWG), dim3(256), 0, stream>>>(xbf, bt, sc, out);
  } else {
    qlin_fused_kernel<<<dim3(NWG), dim3(256), 0, stream>>>(x, pw, sc, out);
  }
}

// Round 14
// 645.755 us; speedup vs baseline: 11.8206x; 1.0841x over previous
//
#include <hip/hip_runtime.h>
#include <hip/hip_bf16.h>

// Ternary-quantized linear: out[M,N] = x[M,K] . W^T,  W[n,k] = q[n,k]*scale[n].
// R14: R7 geometry + BK=128 double-buffer (halve sync events at the same
//      2-waves/SIMD occupancy; acc regs cap occupancy anyway). A buffer = two
//      K-halves, each byte-identical to R7's LDS image; B = [2][256][16B]
//      packed. Loop = R8's dbuf 2-barrier pattern with counted vmcnt(10)
//      (never 0 in-loop). No setprio (R7's best config). Pre-pass unchanged.

#define M_DIM 8192
#define N_DIM 11008
#define K_DIM 4096
#define BM 128
#define BN 256
#define KT32 32                     // K-tiles of 128
#define NB_N 43
#define NWG 2752                    // 64*43, %8 == 0

#define XBF_BYTES ((size_t)M_DIM * K_DIM * 2)        // 67108864
#define BT_BYTES  ((size_t)N_DIM * K_DIM / 4)        // 11272192
#define WS_NEED   (XBF_BYTES + BT_BYTES)             // 78381056

typedef __attribute__((ext_vector_type(8))) short bf16x8;
typedef __attribute__((ext_vector_type(4))) float f32x4;

__device__ inline unsigned int bf16b(float f) {
  union { __hip_bfloat16 h; unsigned short u; } cv;
  cv.h = __float2bfloat16(f);
  return (unsigned int)cv.u;
}

__device__ __forceinline__ void gload_lds16(const void* g, void* l) {
  __builtin_amdgcn_global_load_lds(
      (const __attribute__((address_space(1))) unsigned int*)g,
      (__attribute__((address_space(3))) unsigned int*)l, 16, 0, 0);
}

// ---------------- pre-pass: x fp32->bf16 ; PW one-byte-per-int32 -> tight bytes
#define XCVT_BLOCKS 16384   // 16384*256*8 = 33554432 floats
#define PACK_BLOCKS 5504    // 5504*256*8  = 11272192 int32s
__global__ __launch_bounds__(256)
void xcvt_kernel(const float* __restrict__ X, unsigned short* __restrict__ Xbf) {
  const size_t i8 = ((size_t)blockIdx.x * 256 + threadIdx.x) * 8;
  float4 a = *(const float4*)(X + i8);
  float4 c = *(const float4*)(X + i8 + 4);
  uint4 o;
  o.x = bf16b(a.x) | (bf16b(a.y) << 16);
  o.y = bf16b(a.z) | (bf16b(a.w) << 16);
  o.z = bf16b(c.x) | (bf16b(c.y) << 16);
  o.w = bf16b(c.z) | (bf16b(c.w) << 16);
  *(uint4*)(Xbf + i8) = o;
}

__global__ __launch_bounds__(256)
void btight_kernel(const int* __restrict__ PW, unsigned char* __restrict__ Bt) {
  const size_t i8 = ((size_t)blockIdx.x * 256 + threadIdx.x) * 8;
  int4 p = *(const int4*)(PW + i8);
  int4 q = *(const int4*)(PW + i8 + 4);
  uint2 o;
  o.x = (unsigned)(p.x & 255) | ((unsigned)(p.y & 255) << 8) |
        ((unsigned)(p.z & 255) << 16) | ((unsigned)(p.w & 255) << 24);
  o.y = (unsigned)(q.x & 255) | ((unsigned)(q.y & 255) << 8) |
        ((unsigned)(q.z & 255) << 16) | ((unsigned)(q.w & 255) << 24);
  *(uint2*)(Bt + i8) = o;
}

// ---------------- main: 128x256 block, 4 waves of 128x64, BK=128 dbuf ----
__global__ __launch_bounds__(256, 2)
void qlin_bk128_kernel(const unsigned short* __restrict__ Xbf,
                       const unsigned char* __restrict__ Bt,
                       const float* __restrict__ SC, float* __restrict__ OUT) {
  __shared__ unsigned short As[2][2][8192];  // [buf][khalf][128 rows x 64 cols] = 64 KB
  __shared__ unsigned char  Bs[2][2][4096];  // [buf][khalf][256 rows x 16 B]   = 16 KB

  const int tid = threadIdx.x;
  const int lane = tid & 63;
  const int w = tid >> 6;

  const int wg = blockIdx.x;
  const int swz = (wg & 7) * (NWG / 8) + (wg >> 3);
  const int bm = swz / NB_N;
  const int bn = swz - bm * NB_N;

  // A stage map (R7-verified per khalf): 4 gload_lds/thread/khalf.
  // LDS o = w*4096B + i*1024B + lane*16B -> row = w*32+i*8+(lane>>3), slot=lane&7.
  // Source chunk c = slot ^ (row&7); row&7 == lane>>3 (pre-swizzled source).
  const int l3 = lane >> 3;
  const char* ab0 = (const char*)Xbf +
      (size_t)(bm * BM + w * 32 + l3) * (K_DIM * 2) + ((lane & 7) ^ l3) * 16;
  // B stage: per khalf 1 gload_lds/wave; row w*64+lane, 16 B.
  const char* bb = (const char*)Bt + (size_t)(bn * BN + w * 64 + lane) * (K_DIM / 4);

  // 10 loads per STAGE (8 A + 2 B)
#define STAGE(IDX, KT_) do {                                                   \
    _Pragma("unroll")                                                          \
    for (int h = 0; h < 2; ++h) {                                              \
      unsigned short* ad_ = &As[IDX][h][w * 2048];                             \
      const char* as_ = ab0 + (KT_) * 256 + h * 128;                           \
      gload_lds16(as_,           ad_);                                         \
      gload_lds16(as_ + 65536,   ad_ + 512);                                   \
      gload_lds16(as_ + 131072,  ad_ + 1024);                                  \
      gload_lds16(as_ + 196608,  ad_ + 1536);                                  \
      gload_lds16(bb + (KT_) * 32 + h * 16, &Bs[IDX][h][w * 1024]);            \
    }                                                                          \
  } while (0)

  f32x4 acc[8][4];
#pragma unroll
  for (int i = 0; i < 8; ++i)
#pragma unroll
    for (int j = 0; j < 4; ++j) acc[i][j] = (f32x4){0.f, 0.f, 0.f, 0.f};

  // fragment geometry (R7)
  const int l4 = lane >> 4;
  const int axor = lane & 7;
  const int arow = (lane & 15) * 128;
  const int hb = l4 >> 1;
  const unsigned hoff = (unsigned)(l4 & 1) * 16;
  const int rbase = (w * 64 + (lane & 15)) * 16 + hb * 4;

#define COMPUTE(B_) do {                                                        \
    _Pragma("unroll")                                                           \
    for (int kk = 0; kk < 4; ++kk) {                                            \
      const int h_ = kk >> 1;                                                   \
      const int kp_ = kk & 1;                                                   \
      const char* asb_ = (const char*)&As[B_][h_][0];                           \
      const unsigned char* bsb_ = &Bs[B_][h_][0];                               \
      bf16x8 af[8];                                                             \
      _Pragma("unroll")                                                         \
      for (int m = 0; m < 8; ++m)                                               \
        af[m] = *(const bf16x8*)(asb_ + m * 2048 + arow +                       \
                                 (((kp_ * 4 + l4) ^ axor) << 4));               \
      _Pragma("unroll")                                                         \
      for (int n = 0; n < 4; ++n) {                                             \
        const unsigned d = *(const unsigned*)(bsb_ + rbase + n * 256 + kp_ * 8); \
        const unsigned w16 = (d >> hoff) & 0xFFFFu;                             \
        const unsigned u = w16 | (w16 << 14);                                   \
        union { uint4 s; bf16x8 v; } bfr;                                       \
        bfr.s.x = ((u << 14) & 0xC000C000u) + 0x40004000u;                      \
        bfr.s.y = ((u << 10) & 0xC000C000u) + 0x40004000u;                      \
        bfr.s.z = ((u << 6)  & 0xC000C000u) + 0x40004000u;                      \
        bfr.s.w = ((u << 2)  & 0xC000C000u) + 0x40004000u;                      \
        _Pragma("unroll")                                                       \
        for (int m = 0; m < 8; ++m)                                             \
          acc[m][n] = __builtin_amdgcn_mfma_f32_16x16x32_bf16(af[m], bfr.v,     \
                                                              acc[m][n], 0, 0, 0); \
      }                                                                         \
    }                                                                           \
  } while (0)

  // ---- main loop: dbuf, counted vmcnt(10), 2 raw barriers per kt ----
  STAGE(0, 0);                                   // 10 loads in flight
  int cur = 0;
  for (int kt = 0; kt < KT32 - 1; ++kt) {
    STAGE(cur ^ 1, kt + 1);                      // 20 in flight
    asm volatile("s_waitcnt vmcnt(10)" ::: "memory");  // cur's 10 done; nxt's fly
    __builtin_amdgcn_s_barrier();                // all waves: cur ready
    COMPUTE(cur);
    asm volatile("s_waitcnt lgkmcnt(0)" ::: "memory"); // my reads of cur done
    __builtin_amdgcn_s_barrier();                // all waves done reading cur
    cur ^= 1;
  }
  asm volatile("s_waitcnt vmcnt(0)" ::: "memory");     // tail: last buffer
  __builtin_amdgcn_s_barrier();
  COMPUTE(cur);
#undef STAGE
#undef COMPUTE

  // epilogue: acc * (-0.5*scale[col]); C/D: col=lane&15, row=(lane>>4)*4+r
  const int gc0 = bn * BN + w * 64 + (lane & 15);
  const int gr0 = bm * BM + (l4 << 2);
  float sc[4];
#pragma unroll
  for (int n = 0; n < 4; ++n) sc[n] = -0.5f * SC[gc0 + n * 16];
#pragma unroll
  for (int m = 0; m < 8; ++m)
#pragma unroll
    for (int n = 0; n < 4; ++n)
#pragma unroll
      for (int r = 0; r < 4; ++r)
        OUT[(size_t)(gr0 + m * 16 + r) * N_DIM + gc0 + n * 16] = acc[m][n][r] * sc[n];
}

// ---------------- fallback: R5 fused kernel (ws too small) ----------
#define BSTRIDE 20
__global__ __launch_bounds__(256, 2)
void qlin_fused_kernel(const float* __restrict__ X, const int* __restrict__ PW,
                       const float* __restrict__ SC, float* __restrict__ OUT) {
  __shared__ unsigned short Asf[128 * 64];
  __shared__ unsigned char Bp[256 * BSTRIDE];

  const int tid = threadIdx.x;
  const int wg = blockIdx.x;
  const int swz = (wg & 7) * (NWG / 8) + (wg >> 3);
  const int bm = swz / NB_N;
  const int bn = swz - bm * NB_N;

  const int lane = tid & 63;
  const int wave = tid >> 6;
  const int wr = wave >> 1;
  const int wc = wave & 1;

  const int arow = tid >> 3;
  const int ac8  = tid & 7;
  const float* xptr = X + (size_t)(bm * 128 + arow) * K_DIM + ac8 * 8;
  const unsigned int aswz = ((unsigned)arow & 7u) << 4;

  const int bc  = tid & 3;
  const int br0 = tid >> 2;
  const int* pwptr = PW + (size_t)(bn * 256 + br0) * (K_DIM / 4) + bc * 4;
  const int bwoff = (bc & 1) * 8 + (bc >> 1) * 2;

  f32x4 acc[4][8];
#pragma unroll
  for (int i = 0; i < 4; ++i)
#pragma unroll
    for (int j = 0; j < 8; ++j) acc[i][j] = (f32x4){0.f, 0.f, 0.f, 0.f};

  float4 av[4][2];
  int4 bv[4];
#pragma unroll
  for (int j = 0; j < 4; ++j) {
    av[j][0] = *(const float4*)(xptr + (size_t)(32 * j) * K_DIM);
    av[j][1] = *(const float4*)(xptr + (size_t)(32 * j) * K_DIM + 4);
  }
#pragma unroll
  for (int j = 0; j < 4; ++j)
    bv[j] = *(const int4*)(pwptr + (size_t)(64 * j) * (K_DIM / 4));

  for (int kt = 0; kt < 64; ++kt) {
    __syncthreads();
#pragma unroll
    for (int j = 0; j < 4; ++j) {
      uint4 wv;
      wv.x = bf16b(av[j][0].x) | (bf16b(av[j][0].y) << 16);
      wv.y = bf16b(av[j][0].z) | (bf16b(av[j][0].w) << 16);
      wv.z = bf16b(av[j][1].x) | (bf16b(av[j][1].y) << 16);
      wv.w = bf16b(av[j][1].z) | (bf16b(av[j][1].w) << 16);
      *(uint4*)((char*)Asf + (arow + 32 * j) * 128 + (((unsigned)ac8 * 16u) ^ aswz)) = wv;
    }
#pragma unroll
    for (int j = 0; j < 4; ++j) {
      const unsigned int ulo = ((unsigned)bv[j].x & 255u) | (((unsigned)bv[j].y & 255u) << 8);
      const unsigned int uhi = ((unsigned)bv[j].z & 255u) | (((unsigned)bv[j].w & 255u) << 8);
      unsigned char* dst = Bp + (br0 + 64 * j) * BSTRIDE + bwoff;
      *(unsigned short*)(dst)     = (unsigned short)ulo;
      *(unsigned short*)(dst + 4) = (unsigned short)uhi;
    }
    __syncthreads();

    if (kt + 1 < 64) {
#pragma unroll
      for (int j = 0; j < 4; ++j) {
        av[j][0] = *(const float4*)(xptr + (kt + 1) * 64 + (size_t)(32 * j) * K_DIM);
        av[j][1] = *(const float4*)(xptr + (kt + 1) * 64 + (size_t)(32 * j) * K_DIM + 4);
      }
#pragma unroll
      for (int j = 0; j < 4; ++j)
        bv[j] = *(const int4*)(pwptr + (kt + 1) * 16 + (size_t)(64 * j) * (K_DIM / 4));
    }

    const int bh = lane >> 4;
    const int bcol0 = wc * 128 + (lane & 15);
    unsigned int d[8];
#pragma unroll
    for (int n = 0; n < 8; ++n)
      d[n] = *(const unsigned int*)(Bp + (bcol0 + n * 16) * BSTRIDE + bh * 4);

    const unsigned int rswz = ((unsigned)lane & 7u) << 4;
#pragma unroll
    for (int kk = 0; kk < 2; ++kk) {
      bf16x8 af[4];
      const unsigned int coff = (((unsigned)(kk * 4 + (lane >> 4))) * 16u) ^ rswz;
#pragma unroll
      for (int m = 0; m < 4; ++m)
        af[m] = *(const bf16x8*)((const char*)Asf + (wr * 64 + m * 16 + (lane & 15)) * 128 + coff);
#pragma unroll
      for (int n = 0; n < 8; ++n) {
        const unsigned int w16 = kk ? (d[n] >> 16) : (d[n] & 0xFFFFu);
        const unsigned int u = w16 | (w16 << 14);
        union { uint4 s; bf16x8 v; } bfr;
        bfr.s.x = ((u << 14) & 0xC000C000u) + 0x40004000u;
        bfr.s.y = ((u << 10) & 0xC000C000u) + 0x40004000u;
        bfr.s.z = ((u << 6)  & 0xC000C000u) + 0x40004000u;
        bfr.s.w = ((u << 2)  & 0xC000C000u) + 0x40004000u;
#pragma unroll
        for (int m = 0; m < 4; ++m)
          acc[m][n] = __builtin_amdgcn_mfma_f32_16x16x32_bf16(af[m], bfr.v, acc[m][n], 0, 0, 0);
      }
    }
  }

  const int gc0 = bn * 256 + wc * 128 + (lane & 15);
  const int gr0 = bm * 128 + wr * 64 + ((lane >> 4) << 2);
  float sc[8];
#pragma unroll
  for (int n = 0; n < 8; ++n) sc[n] = -0.5f * SC[gc0 + n * 16];
#pragma unroll
  for (int m = 0; m < 4; ++m)
#pragma unroll
    for (int n = 0; n < 8; ++n)
#pragma unroll
      for (int r = 0; r < 4; ++r)
        OUT[(size_t)(gr0 + m * 16 + r) * N_DIM + gc0 + n * 16] = acc[m][n][r] * sc[n];
}

extern "C" void kernel_launch(void* const* d_in, const int* in_sizes, int n_in,
                              void* d_out, int out_size, void* d_ws, size_t ws_size,
                              hipStream_t stream) {
  const float* x  = (const float*)d_in[0];
  const int*   pw = (const int*)d_in[1];
  const float* sc = (const float*)d_in[2];
  float* out = (float*)d_out;
  (void)in_sizes; (void)n_in; (void)out_size;

  if (ws_size >= WS_NEED) {
    unsigned short* xbf = (unsigned short*)d_ws;
    unsigned char* bt = (unsigned char*)d_ws + XBF_BYTES;
    xcvt_kernel<<<dim3(XCVT_BLOCKS), dim3(256), 0, stream>>>(x, xbf);
    btight_kernel<<<dim3(PACK_BLOCKS), dim3(256), 0, stream>>>(pw, bt);
    qlin_bk128_kernel<<<dim3(NWG), dim3(256), 0, stream>>>(xbf, bt, sc, out);
  } else {
    qlin_fused_kernel<<<dim3(NWG), dim3(256), 0, stream>>>(x, pw, sc, out);
  }
}